// Round 1
// baseline (1821.518 us; speedup 1.0000x reference)
//
#include <hip/hip_runtime.h>
#include <math.h>

#define N 8192
#define D 128
#define KSEL 16
#define RB 4
#define TB 256
#define NEG_INF_F (-1e30f)

// ---------- kernel 1: per-row inverse L2 norm ----------
__global__ void k_invnorm(const float* __restrict__ x, float* __restrict__ invn) {
    int row = blockIdx.x;
    int lane = threadIdx.x & 63;
    const float2* x2 = (const float2*)(x + (size_t)row * D);
    float2 a = x2[lane];                       // 64 lanes * 2 = 128 elems
    float s = fmaf(a.x, a.x, a.y * a.y);
#pragma unroll
    for (int off = 32; off > 0; off >>= 1)
        s += __shfl_xor(s, off, 64);
    if (lane == 0) invn[row] = rsqrtf(s);
}

// ---------- kernel 2: fused S-rows + LSE + top-16 ----------
extern __shared__ float Sdyn[];   // RB * N floats = 128 KB

__global__ __launch_bounds__(TB, 1) void k_rows(const float* __restrict__ x,
                                                const float* __restrict__ invn,
                                                float* __restrict__ partials) {
    __shared__ float4 xi4[RB][D / 4];   // 4 rows of x_i, 2 KB
    __shared__ float invni_sh[RB];
    float* S = Sdyn;
    const int tid = threadIdx.x;
    const int i0 = blockIdx.x * RB;

    // stage the 4 "i" rows
    for (int t = tid; t < RB * (D / 4); t += TB) {
        int r = t >> 5, c = t & 31;
        xi4[r][c] = ((const float4*)(x + (size_t)(i0 + r) * D))[c];
    }
    if (tid < RB) invni_sh[tid] = invn[i0 + tid];
    __syncthreads();

    float inv_i[RB];
#pragma unroll
    for (int r = 0; r < RB; ++r) inv_i[r] = invni_sh[r];

    // ---- Phase A: compute 4 full S rows into LDS ----
    for (int t = 0; t < N / TB; ++t) {
        int j = tid + t * TB;
        const float4* xj4 = (const float4*)(x + (size_t)j * D);
        float acc[RB];
#pragma unroll
        for (int r = 0; r < RB; ++r) acc[r] = 0.f;
#pragma unroll 8
        for (int c = 0; c < D / 4; ++c) {
            float4 b = xj4[c];
#pragma unroll
            for (int r = 0; r < RB; ++r) {
                float4 a = xi4[r][c];   // broadcast read, conflict-free
                acc[r] = fmaf(a.x, b.x, acc[r]);
                acc[r] = fmaf(a.y, b.y, acc[r]);
                acc[r] = fmaf(a.z, b.z, acc[r]);
                acc[r] = fmaf(a.w, b.w, acc[r]);
            }
        }
        float vj = invn[j];
#pragma unroll
        for (int r = 0; r < RB; ++r)
            S[r * N + j] = acc[r] * inv_i[r] * vj;   // lane-consecutive, 2-way = free
    }
    __syncthreads();

    // ---- Phase B: wave w owns row w ----
    const int w = tid >> 6;
    const int lane = tid & 63;
    float* Srow = S + w * N;
    const int gi = i0 + w;              // global row index (diag position)

    // 1) row max, diagonal INCLUDED (denominator includes self)
    float m = NEG_INF_F;
#pragma unroll 8
    for (int s = 0; s < N / 64; ++s)
        m = fmaxf(m, Srow[lane + 64 * s]);   // j = lane + 64s: 2-way banks = free
#pragma unroll
    for (int off = 32; off > 0; off >>= 1)
        m = fmaxf(m, __shfl_xor(m, off, 64));

    // 2) sum of exp
    float se = 0.f;
#pragma unroll 8
    for (int s = 0; s < N / 64; ++s)
        se += expf(Srow[lane + 64 * s] - m);
#pragma unroll
    for (int off = 32; off > 0; off >>= 1)
        se += __shfl_xor(se, off, 64);
    float lse = m + logf(se);

    // 3) mask diagonal for top-k. Position gi lives in lane (gi&63)'s stripe,
    //    written and later re-read only by that same lane -> no sync needed.
    if (lane == (gi & 63)) Srow[gi] = NEG_INF_F;

    // 4) per-lane cached argmax over its 128-elem stripe
    float lv = NEG_INF_F;
    int li = lane;
#pragma unroll 8
    for (int s = 0; s < N / 64; ++s) {
        int j = lane + 64 * s;
        float v = Srow[j];
        if (v > lv) { lv = v; li = j; }
    }

    // 5) 16 x (wave argmax + winner-lane rescan)
    float topsum = 0.f;
    for (int it = 0; it < KSEL; ++it) {
        float bv = lv;
        int bi = li;
#pragma unroll
        for (int off = 32; off > 0; off >>= 1) {
            float ov = __shfl_xor(bv, off, 64);
            int oi = __shfl_xor(bi, off, 64);
            if (ov > bv || (ov == bv && oi < bi)) { bv = ov; bi = oi; }
        }
        topsum += bv;
        if ((bi & 63) == lane) {        // unique winner (idx tiebreak)
            Srow[bi] = NEG_INF_F;
            lv = NEG_INF_F; li = lane;
#pragma unroll 8
            for (int s = 0; s < N / 64; ++s) {
                int j = lane + 64 * s;
                float v = Srow[j];
                if (v > lv) { lv = v; li = j; }
            }
        }
    }

    if (lane == 0) partials[gi] = (float)KSEL * lse - topsum;
}

// ---------- kernel 3: deterministic final reduction ----------
__global__ void k_reduce(const float* __restrict__ partials, float* __restrict__ out) {
    __shared__ float sh[TB];
    int tid = threadIdx.x;
    float s = 0.f;
    for (int i = tid; i < N; i += TB) s += partials[i];
    sh[tid] = s;
    __syncthreads();
    for (int st = TB / 2; st > 0; st >>= 1) {
        if (tid < st) sh[tid] += sh[tid + st];
        __syncthreads();
    }
    if (tid == 0) out[0] = sh[0];
}

extern "C" void kernel_launch(void* const* d_in, const int* in_sizes, int n_in,
                              void* d_out, int out_size, void* d_ws, size_t ws_size,
                              hipStream_t stream) {
    const float* x = (const float*)d_in[0];   // [8192, 128] fp32
    float* out = (float*)d_out;               // scalar fp32 loss
    float* invn = (float*)d_ws;               // 8192 floats
    float* partials = invn + N;               // 8192 floats

    // allow 128 KB dynamic LDS on gfx950 (160 KB/CU available)
    hipFuncSetAttribute(reinterpret_cast<const void*>(k_rows),
                        hipFuncAttributeMaxDynamicSharedMemorySize,
                        RB * N * (int)sizeof(float));

    k_invnorm<<<N, 64, 0, stream>>>(x, invn);
    k_rows<<<N / RB, TB, RB * N * sizeof(float), stream>>>(x, invn, partials);
    k_reduce<<<1, TB, 0, stream>>>(partials, out);
}

// Round 2
// 270.458 us; speedup vs baseline: 6.7349x; 6.7349x over previous
//
#include <hip/hip_runtime.h>
#include <math.h>

#define N 8192
#define D 128
#define KSEL 16
#define CH 512            // columns per chunk-block
#define NC (N / CH)       // 16 chunks per row
#define BM 64             // rows per block (4 waves x 16)
#define NEG_INF_F (-1e30f)

typedef __attribute__((ext_vector_type(8))) short short8;
typedef __attribute__((ext_vector_type(8))) unsigned short u16x8;
typedef __attribute__((ext_vector_type(4))) float f32x4;
typedef __attribute__((ext_vector_type(2))) unsigned short ush2;

static __device__ __forceinline__ unsigned short f2bf(float f) {
    unsigned u = __float_as_uint(f);
    u += 0x7FFF + ((u >> 16) & 1);          // RNE
    return (unsigned short)(u >> 16);
}
static __device__ __forceinline__ float bf2f(unsigned short s) {
    return __uint_as_float(((unsigned)s) << 16);
}

// ---------- kernel 1: normalize rows, emit bf16 xn ----------
__global__ void k_normalize(const float* __restrict__ x, unsigned short* __restrict__ xn) {
    int row = blockIdx.x;
    int lane = threadIdx.x;                  // 64 threads
    const float2* x2 = (const float2*)(x + (size_t)row * D);
    float2 a = x2[lane];
    float s = fmaf(a.x, a.x, a.y * a.y);
#pragma unroll
    for (int off = 32; off > 0; off >>= 1) s += __shfl_xor(s, off, 64);
    float inv = rsqrtf(s);
    ush2 h;
    h.x = f2bf(a.x * inv);
    h.y = f2bf(a.y * inv);
    *(ush2*)(xn + (size_t)row * D + lane * 2) = h;
}

// ---------- kernel 2: MFMA S-tile + per-chunk lse parts + per-chunk top-16 ----------
extern __shared__ unsigned short Sall[];     // 4 waves * 16 * 512 ushorts = 64 KB

__global__ __launch_bounds__(256, 2) void k_tiles(const unsigned short* __restrict__ xn,
                                                  float* __restrict__ cm,
                                                  float* __restrict__ cs,
                                                  float* __restrict__ ct) {
    const int tid = threadIdx.x;
    const int w = tid >> 6;
    const int l = tid & 63;
    const int r = l & 15;                    // row-within-wave-tile (A lane map & phase-B row)
    const int p = l >> 4;                    // k-group / col-part
    const int i0 = blockIdx.x * BM;
    const int j0 = blockIdx.y * CH;
    unsigned short* St = Sall + w * (16 * CH);

    // ---- Phase A: 16x512 S tile via MFMA, wave-private ----
    const int arow = i0 + w * 16 + r;
    const unsigned short* ap = xn + (size_t)arow * D + p * 8;
    short8 af0 = *(const short8*)(ap);
    short8 af1 = *(const short8*)(ap + 32);
    short8 af2 = *(const short8*)(ap + 64);
    short8 af3 = *(const short8*)(ap + 96);

    for (int t = 0; t < CH / 16; ++t) {
        int bcol = j0 + t * 16 + r;
        const unsigned short* bp = xn + (size_t)bcol * D + p * 8;
        short8 b0 = *(const short8*)(bp);
        short8 b1 = *(const short8*)(bp + 32);
        short8 b2 = *(const short8*)(bp + 64);
        short8 b3 = *(const short8*)(bp + 96);
        f32x4 acc = {0.f, 0.f, 0.f, 0.f};
        acc = __builtin_amdgcn_mfma_f32_16x16x32_bf16(af0, b0, acc, 0, 0, 0);
        acc = __builtin_amdgcn_mfma_f32_16x16x32_bf16(af1, b1, acc, 0, 0, 0);
        acc = __builtin_amdgcn_mfma_f32_16x16x32_bf16(af2, b2, acc, 0, 0, 0);
        acc = __builtin_amdgcn_mfma_f32_16x16x32_bf16(af3, b3, acc, 0, 0, 0);
#pragma unroll
        for (int q = 0; q < 4; ++q) {        // D: row=(l>>4)*4+q, col=l&15
            int row = p * 4 + q;
            int col = t * 16 + r;
            St[row * CH + (col ^ ((row & 7) << 3))] = f2bf(acc[q]);
        }
    }

    // ---- Phase B: per-row chunk max, exp-sum, top-16 (wave-private, no barrier) ----
    const int gr = i0 + w * 16 + r;          // this lane's row
    const int cb = p * 128;                  // stripe base col (4 lanes/row x 128 cols)
    const int swz = (r & 7) << 3;

    u16x8 u[16];
    float mc = NEG_INF_F;
#pragma unroll
    for (int k = 0; k < 16; ++k) {
        int c0 = (cb + k * 8) ^ swz;
        u[k] = *(const u16x8*)(St + r * CH + c0);
#pragma unroll
        for (int e = 0; e < 8; ++e) mc = fmaxf(mc, bf2f(u[k][e]));
    }
    mc = fmaxf(mc, __shfl_xor(mc, 16, 64));
    mc = fmaxf(mc, __shfl_xor(mc, 32, 64));

    float se = 0.f, lv = NEG_INF_F;
    int li = 0;
#pragma unroll
    for (int k = 0; k < 16; ++k) {
#pragma unroll
        for (int e = 0; e < 8; ++e) {
            float f = bf2f(u[k][e]);
            se += __expf(f - mc);            // diagonal INCLUDED in lse
            int cc = cb + k * 8 + e;
            float eff = ((j0 + cc) == gr) ? NEG_INF_F : f;   // diag masked for top-k
            if (eff > lv) { lv = eff; li = cc; }
        }
    }
    se += __shfl_xor(se, 16, 64);
    se += __shfl_xor(se, 32, 64);
    if (p == 0) {
        cm[(size_t)gr * NC + blockIdx.y] = mc;
        cs[(size_t)gr * NC + blockIdx.y] = se;
    }

    // mask diagonal in LDS so rescans skip it
    int cd = gr - j0;
    if (cd >= 0 && cd < CH && (cd >> 7) == p)
        St[r * CH + (cd ^ swz)] = 0xFF80;    // bf16 -inf

    float* ctrow = ct + (size_t)gr * (NC * KSEL) + blockIdx.y * KSEL;
    for (int it = 0; it < KSEL; ++it) {
        float bv = lv; int bi = li;
        { float ov = __shfl_xor(bv, 16, 64); int oi = __shfl_xor(bi, 16, 64);
          if (ov > bv || (ov == bv && oi < bi)) { bv = ov; bi = oi; } }
        { float ov = __shfl_xor(bv, 32, 64); int oi = __shfl_xor(bi, 32, 64);
          if (ov > bv || (ov == bv && oi < bi)) { bv = ov; bi = oi; } }
        if (p == 0) ctrow[it] = bv;
        if ((bi >> 7) == p) {                // winner lane: remove + rescan its stripe
            St[r * CH + (bi ^ swz)] = 0xFF80;
            float nlv = NEG_INF_F; int nli = 0;
#pragma unroll
            for (int k = 0; k < 16; ++k) {
                int c0 = (cb + k * 8) ^ swz;
                u16x8 v = *(const u16x8*)(St + r * CH + c0);
#pragma unroll
                for (int e = 0; e < 8; ++e) {
                    float f = bf2f(v[e]);
                    if (f > nlv) { nlv = f; nli = cb + k * 8 + e; }
                }
            }
            lv = nlv; li = nli;
        }
    }
}

// ---------- kernel 3: merge chunks per row ----------
__global__ void k_merge(const float* __restrict__ cm, const float* __restrict__ cs,
                        const float* __restrict__ ct, float* __restrict__ partials) {
    int w = threadIdx.x >> 6, l = threadIdx.x & 63;
    int row = blockIdx.x * 4 + w;

    float m = NEG_INF_F, s = 0.f;
    if (l < NC) { m = cm[(size_t)row * NC + l]; s = cs[(size_t)row * NC + l]; }
    float M = m;
#pragma unroll
    for (int off = 32; off > 0; off >>= 1) M = fmaxf(M, __shfl_xor(M, off, 64));
    float z = s * __expf(m - M);             // s=0 for inactive lanes -> 0
#pragma unroll
    for (int off = 32; off > 0; off >>= 1) z += __shfl_xor(z, off, 64);
    float lse = M + logf(z);

    // top-16 of the 256 per-chunk candidates (exact superset of global top-16)
    const float4* cp = (const float4*)(ct + (size_t)row * (NC * KSEL));
    float4 v = cp[l];
    float v0 = v.x, v1 = v.y, v2 = v.z, v3 = v.w;
    float topsum = 0.f;
    for (int it = 0; it < KSEL; ++it) {
        float b = fmaxf(fmaxf(v0, v1), fmaxf(v2, v3));
        float bv = b; int bl = l;
#pragma unroll
        for (int off = 32; off > 0; off >>= 1) {
            float ov = __shfl_xor(bv, off, 64);
            int ol = __shfl_xor(bl, off, 64);
            if (ov > bv || (ov == bv && ol < bl)) { bv = ov; bl = ol; }
        }
        topsum += bv;
        if (bl == l) {                       // remove exactly one instance
            if (v0 == bv)      v0 = NEG_INF_F;
            else if (v1 == bv) v1 = NEG_INF_F;
            else if (v2 == bv) v2 = NEG_INF_F;
            else               v3 = NEG_INF_F;
        }
    }
    if (l == 0) partials[row] = (float)KSEL * lse - topsum;
}

// ---------- kernel 4: deterministic final reduction ----------
__global__ void k_reduce(const float* __restrict__ partials, float* __restrict__ out) {
    __shared__ float sh[256];
    int tid = threadIdx.x;
    float s = 0.f;
    for (int i = tid; i < N; i += 256) s += partials[i];
    sh[tid] = s;
    __syncthreads();
    for (int st = 128; st > 0; st >>= 1) {
        if (tid < st) sh[tid] += sh[tid + st];
        __syncthreads();
    }
    if (tid == 0) out[0] = sh[0];
}

extern "C" void kernel_launch(void* const* d_in, const int* in_sizes, int n_in,
                              void* d_out, int out_size, void* d_ws, size_t ws_size,
                              hipStream_t stream) {
    const float* x = (const float*)d_in[0];
    float* out = (float*)d_out;

    unsigned short* xn = (unsigned short*)d_ws;                 // 2 MB
    float* cm = (float*)((char*)d_ws + (2u << 20));             // 512 KB
    float* cs = cm + (size_t)N * NC;                            // 512 KB
    float* ct = cs + (size_t)N * NC;                            // 8 MB
    float* partials = ct + (size_t)N * NC * KSEL;               // 32 KB

    hipFuncSetAttribute(reinterpret_cast<const void*>(k_tiles),
                        hipFuncAttributeMaxDynamicSharedMemorySize, 65536);

    k_normalize<<<N, 64, 0, stream>>>(x, xn);
    k_tiles<<<dim3(N / BM, NC), 256, 65536, stream>>>(xn, cm, cs, ct);
    k_merge<<<N / 4, 256, 0, stream>>>(cm, cs, ct, partials);
    k_reduce<<<1, 256, 0, stream>>>(partials, out);
}

// Round 3
// 269.646 us; speedup vs baseline: 6.7552x; 1.0030x over previous
//
#include <hip/hip_runtime.h>
#include <math.h>

#define N 8192
#define D 128
#define KSEL 16
#define CH 512            // columns per chunk-block
#define NC (N / CH)       // 16 chunks per row
#define BM 64             // rows per block (4 waves x 16)
#define NEG_INF_F (-1e30f)

typedef __attribute__((ext_vector_type(8))) short short8;
typedef __attribute__((ext_vector_type(8))) unsigned short u16x8;
typedef __attribute__((ext_vector_type(4))) float f32x4;
typedef __attribute__((ext_vector_type(2))) unsigned short ush2;

static __device__ __forceinline__ unsigned short f2bf(float f) {
    unsigned u = __float_as_uint(f);
    u += 0x7FFF + ((u >> 16) & 1);          // RNE
    return (unsigned short)(u >> 16);
}
static __device__ __forceinline__ float bf2f(unsigned short s) {
    return __uint_as_float(((unsigned)s) << 16);
}

// ---------- kernel 1: normalize rows, emit bf16 xn ----------
__global__ void k_normalize(const float* __restrict__ x, unsigned short* __restrict__ xn) {
    int row = blockIdx.x;
    int lane = threadIdx.x;                  // 64 threads
    const float2* x2 = (const float2*)(x + (size_t)row * D);
    float2 a = x2[lane];
    float s = fmaf(a.x, a.x, a.y * a.y);
#pragma unroll
    for (int off = 32; off > 0; off >>= 1) s += __shfl_xor(s, off, 64);
    float inv = rsqrtf(s);
    ush2 h;
    h.x = f2bf(a.x * inv);
    h.y = f2bf(a.y * inv);
    *(ush2*)(xn + (size_t)row * D + lane * 2) = h;
}

// ---------- kernel 2: MFMA S-tile + per-chunk lse parts + per-lane top-4 ----------
extern __shared__ unsigned short Sall[];     // 4 waves * 16 * 512 ushorts = 64 KB

__global__ __launch_bounds__(256, 2) void k_tiles(const unsigned short* __restrict__ xn,
                                                  float* __restrict__ cm,
                                                  float* __restrict__ cs,
                                                  float* __restrict__ ct) {
    const int tid = threadIdx.x;
    const int w = tid >> 6;
    const int l = tid & 63;
    const int r = l & 15;                    // row-within-wave-tile
    const int p = l >> 4;                    // k-group / col-part
    const int i0 = blockIdx.x * BM;
    const int j0 = blockIdx.y * CH;
    unsigned short* St = Sall + w * (16 * CH);

    // ---- Phase A: 16x512 S tile via MFMA, wave-private ----
    const int arow = i0 + w * 16 + r;
    const unsigned short* ap = xn + (size_t)arow * D + p * 8;
    short8 af0 = *(const short8*)(ap);
    short8 af1 = *(const short8*)(ap + 32);
    short8 af2 = *(const short8*)(ap + 64);
    short8 af3 = *(const short8*)(ap + 96);

    for (int t = 0; t < CH / 16; ++t) {
        int bcol = j0 + t * 16 + r;
        const unsigned short* bp = xn + (size_t)bcol * D + p * 8;
        short8 b0 = *(const short8*)(bp);
        short8 b1 = *(const short8*)(bp + 32);
        short8 b2 = *(const short8*)(bp + 64);
        short8 b3 = *(const short8*)(bp + 96);
        f32x4 acc = {0.f, 0.f, 0.f, 0.f};
        acc = __builtin_amdgcn_mfma_f32_16x16x32_bf16(af0, b0, acc, 0, 0, 0);
        acc = __builtin_amdgcn_mfma_f32_16x16x32_bf16(af1, b1, acc, 0, 0, 0);
        acc = __builtin_amdgcn_mfma_f32_16x16x32_bf16(af2, b2, acc, 0, 0, 0);
        acc = __builtin_amdgcn_mfma_f32_16x16x32_bf16(af3, b3, acc, 0, 0, 0);
#pragma unroll
        for (int q = 0; q < 4; ++q) {        // D layout: row=(l>>4)*4+q, col=l&15
            int row = p * 4 + q;
            int col = t * 16 + r;
            St[row * CH + (col ^ ((row & 7) << 3))] = f2bf(acc[q]);
        }
    }

    // ---- Phase B: per-row chunk max/exp-sum + per-lane branchless top-4 ----
    // Diagonal is NOT masked: S_ii (~1.0) is the guaranteed max of the row's
    // candidates; the merge kernel extracts top-17 and drops the max.
    const int gr = i0 + w * 16 + r;
    const int cb = p * 128;
    const int swz = (r & 7) << 3;

    u16x8 u[16];
#pragma unroll
    for (int k = 0; k < 16; ++k)
        u[k] = *(const u16x8*)(St + r * CH + ((cb + k * 8) ^ swz));

    // pass 1: sorted top-4 insert (min/max network, 7 ops/elem); c0 = stripe max
    float c0 = NEG_INF_F, c1 = NEG_INF_F, c2 = NEG_INF_F, c3 = NEG_INF_F;
#pragma unroll
    for (int k = 0; k < 16; ++k) {
#pragma unroll
        for (int e = 0; e < 8; ++e) {
            float f = bf2f(u[k][e]);
            float m0 = fminf(c0, f);  c0 = fmaxf(c0, f);
            float m1 = fminf(c1, m0); c1 = fmaxf(c1, m0);
            float m2 = fminf(c2, m1); c2 = fmaxf(c2, m1);
            c3 = fmaxf(c3, m2);
        }
    }

    // chunk max for this row (diag included) = numerical stabilizer
    float mc = c0;
    mc = fmaxf(mc, __shfl_xor(mc, 16, 64));
    mc = fmaxf(mc, __shfl_xor(mc, 32, 64));

    // pass 2: exp-sum (diag included, as reference requires)
    float se = 0.f;
#pragma unroll
    for (int k = 0; k < 16; ++k)
#pragma unroll
        for (int e = 0; e < 8; ++e)
            se += __expf(bf2f(u[k][e]) - mc);
    se += __shfl_xor(se, 16, 64);
    se += __shfl_xor(se, 32, 64);

    if (p == 0) {
        cm[(size_t)gr * NC + blockIdx.y] = mc;
        cs[(size_t)gr * NC + blockIdx.y] = se;
    }
    float4 cand = make_float4(c0, c1, c2, c3);
    *(float4*)(ct + (size_t)gr * (NC * KSEL) + blockIdx.y * KSEL + p * 4) = cand;
}

// ---------- kernel 3: merge chunks per row ----------
__global__ void k_merge(const float* __restrict__ cm, const float* __restrict__ cs,
                        const float* __restrict__ ct, float* __restrict__ partials) {
    int w = threadIdx.x >> 6, l = threadIdx.x & 63;
    int row = blockIdx.x * 4 + w;

    float m = NEG_INF_F, s = 0.f;
    if (l < NC) { m = cm[(size_t)row * NC + l]; s = cs[(size_t)row * NC + l]; }
    float M = m;
#pragma unroll
    for (int off = 32; off > 0; off >>= 1) M = fmaxf(M, __shfl_xor(M, off, 64));
    float z = s * __expf(m - M);             // s=0 for inactive lanes -> 0
#pragma unroll
    for (int off = 32; off > 0; off >>= 1) z += __shfl_xor(z, off, 64);
    float lse = M + logf(z);

    // top-17 of the 256 candidates; iteration 0 extracts the diagonal (global
    // max of the candidate set) and is excluded from the sum.
    const float4* cp = (const float4*)(ct + (size_t)row * (NC * KSEL));
    float4 v = cp[l];
    float v0 = v.x, v1 = v.y, v2 = v.z, v3 = v.w;
    float topsum = 0.f;
    for (int it = 0; it < KSEL + 1; ++it) {
        float b = fmaxf(fmaxf(v0, v1), fmaxf(v2, v3));
        float bv = b; int bl = l;
#pragma unroll
        for (int off = 32; off > 0; off >>= 1) {
            float ov = __shfl_xor(bv, off, 64);
            int ol = __shfl_xor(bl, off, 64);
            if (ov > bv || (ov == bv && ol < bl)) { bv = ov; bl = ol; }
        }
        if (it > 0) topsum += bv;
        if (bl == l) {                       // remove exactly one instance
            if (v0 == bv)      v0 = NEG_INF_F;
            else if (v1 == bv) v1 = NEG_INF_F;
            else if (v2 == bv) v2 = NEG_INF_F;
            else               v3 = NEG_INF_F;
        }
    }
    if (l == 0) partials[row] = (float)KSEL * lse - topsum;
}

// ---------- kernel 4: deterministic final reduction ----------
__global__ void k_reduce(const float* __restrict__ partials, float* __restrict__ out) {
    __shared__ float sh[256];
    int tid = threadIdx.x;
    float s = 0.f;
    for (int i = tid; i < N; i += 256) s += partials[i];
    sh[tid] = s;
    __syncthreads();
    for (int st = 128; st > 0; st >>= 1) {
        if (tid < st) sh[tid] += sh[tid + st];
        __syncthreads();
    }
    if (tid == 0) out[0] = sh[0];
}

extern "C" void kernel_launch(void* const* d_in, const int* in_sizes, int n_in,
                              void* d_out, int out_size, void* d_ws, size_t ws_size,
                              hipStream_t stream) {
    const float* x = (const float*)d_in[0];
    float* out = (float*)d_out;

    unsigned short* xn = (unsigned short*)d_ws;                 // 2 MB
    float* cm = (float*)((char*)d_ws + (2u << 20));             // 512 KB
    float* cs = cm + (size_t)N * NC;                            // 512 KB
    float* ct = cs + (size_t)N * NC;                            // 8 MB
    float* partials = ct + (size_t)N * NC * KSEL;               // 32 KB

    hipFuncSetAttribute(reinterpret_cast<const void*>(k_tiles),
                        hipFuncAttributeMaxDynamicSharedMemorySize, 65536);

    k_normalize<<<N, 64, 0, stream>>>(x, xn);
    k_tiles<<<dim3(N / BM, NC), 256, 65536, stream>>>(xn, cm, cs, ct);
    k_merge<<<N / 4, 256, 0, stream>>>(cm, cs, ct, partials);
    k_reduce<<<1, 256, 0, stream>>>(partials, out);
}

// Round 4
// 175.738 us; speedup vs baseline: 10.3650x; 1.5344x over previous
//
#include <hip/hip_runtime.h>
#include <math.h>

#define N 8192
#define D 128
#define KSEL 16
#define CH 512            // columns per chunk (per wave)
#define NC (N / CH)       // 16 chunks per row
#define BM 64             // rows per block (4 waves x 16)
#define NEG_INF_F (-1e30f)

typedef __attribute__((ext_vector_type(8))) short short8;
typedef __attribute__((ext_vector_type(4))) float f32x4;
typedef __attribute__((ext_vector_type(2))) unsigned short ush2;

static __device__ __forceinline__ unsigned short f2bf(float f) {
    unsigned u = __float_as_uint(f);
    u += 0x7FFF + ((u >> 16) & 1);          // RNE
    return (unsigned short)(u >> 16);
}

// branchless sorted top-4 insert (c0 >= c1 >= c2 >= c3)
static __device__ __forceinline__ void ins4(float& c0, float& c1, float& c2, float& c3, float f) {
    float m0 = fminf(c0, f);  c0 = fmaxf(c0, f);
    float m1 = fminf(c1, m0); c1 = fmaxf(c1, m0);
    float m2 = fminf(c2, m1); c2 = fmaxf(c2, m1);
    c3 = fmaxf(c3, m2);
}

// ---------- kernel 1: normalize rows, emit bf16 xn ----------
__global__ void k_normalize(const float* __restrict__ x, unsigned short* __restrict__ xn) {
    int row = blockIdx.x;
    int lane = threadIdx.x;                  // 64 threads
    const float2* x2 = (const float2*)(x + (size_t)row * D);
    float2 a = x2[lane];
    float s = fmaf(a.x, a.x, a.y * a.y);
#pragma unroll
    for (int off = 32; off > 0; off >>= 1) s += __shfl_xor(s, off, 64);
    float inv = rsqrtf(s);
    ush2 h;
    h.x = f2bf(a.x * inv);
    h.y = f2bf(a.y * inv);
    *(ush2*)(xn + (size_t)row * D + lane * 2) = h;
}

// ---------- kernel 2: MFMA + fused in-register exp-sum / top-4 epilogue ----------
// No LDS, no S materialization. Lane (p,r) owns rows p*4+q (q=0..3) at cols
// {j0 + t*16 + r}. exp uses stabilizer 0 (S in [-1,1] -> exp in [.37, 2.72]).
// Diagonal stays IN the exp-sum (reference includes self) and IN the top-4
// candidates (S_ii ~ 1.0 is the guaranteed candidate max; merge drops it).
__global__ __launch_bounds__(256, 4) void k_tiles(const unsigned short* __restrict__ xn,
                                                  float* __restrict__ cs,
                                                  float* __restrict__ ct) {
    const int tid = threadIdx.x;
    const int w = tid >> 6;
    const int l = tid & 63;
    const int r = l & 15;
    const int p = l >> 4;
    const int i0 = blockIdx.x * BM;
    const int j0 = blockIdx.y * CH;
    const int by = blockIdx.y;

    // A fragments: 16 rows of this wave's tile, lane reads row r, k-group p
    const int arow = i0 + w * 16 + r;
    const unsigned short* ap = xn + (size_t)arow * D + p * 8;
    short8 af0 = *(const short8*)(ap);
    short8 af1 = *(const short8*)(ap + 32);
    short8 af2 = *(const short8*)(ap + 64);
    short8 af3 = *(const short8*)(ap + 96);

    float sE[4];
    float cA[4][4];
#pragma unroll
    for (int q = 0; q < 4; ++q) {
        sE[q] = 0.f;
        cA[q][0] = cA[q][1] = cA[q][2] = cA[q][3] = NEG_INF_F;
    }

    for (int t = 0; t < CH / 16; ++t) {
        int bcol = j0 + t * 16 + r;
        const unsigned short* bp = xn + (size_t)bcol * D + p * 8;
        short8 b0 = *(const short8*)(bp);
        short8 b1 = *(const short8*)(bp + 32);
        short8 b2 = *(const short8*)(bp + 64);
        short8 b3 = *(const short8*)(bp + 96);
        f32x4 acc = {0.f, 0.f, 0.f, 0.f};
        acc = __builtin_amdgcn_mfma_f32_16x16x32_bf16(af0, b0, acc, 0, 0, 0);
        acc = __builtin_amdgcn_mfma_f32_16x16x32_bf16(af1, b1, acc, 0, 0, 0);
        acc = __builtin_amdgcn_mfma_f32_16x16x32_bf16(af2, b2, acc, 0, 0, 0);
        acc = __builtin_amdgcn_mfma_f32_16x16x32_bf16(af3, b3, acc, 0, 0, 0);
#pragma unroll
        for (int q = 0; q < 4; ++q) {
            float v = acc[q];
            sE[q] += __expf(v);
            ins4(cA[q][0], cA[q][1], cA[q][2], cA[q][3], v);
        }
    }

    // merge top-4 across 4-lane subgroups (same p, r-subgroups of 4):
    // result = top-4 per 128-col stripe, 4 candidate sets per row per chunk
#pragma unroll
    for (int o = 1; o <= 2; o <<= 1) {
#pragma unroll
        for (int q = 0; q < 4; ++q) {
            float o0 = __shfl_xor(cA[q][0], o, 64);
            float o1 = __shfl_xor(cA[q][1], o, 64);
            float o2 = __shfl_xor(cA[q][2], o, 64);
            float o3 = __shfl_xor(cA[q][3], o, 64);
            ins4(cA[q][0], cA[q][1], cA[q][2], cA[q][3], o0);
            ins4(cA[q][0], cA[q][1], cA[q][2], cA[q][3], o1);
            ins4(cA[q][0], cA[q][1], cA[q][2], cA[q][3], o2);
            ins4(cA[q][0], cA[q][1], cA[q][2], cA[q][3], o3);
        }
    }

    // full 16-lane exp-sum reduce (same p group)
#pragma unroll
    for (int o = 1; o <= 8; o <<= 1)
#pragma unroll
        for (int q = 0; q < 4; ++q)
            sE[q] += __shfl_xor(sE[q], o, 64);

    const int rowbase = i0 + w * 16 + p * 4;
    if ((r & 3) == 0) {
        int rG = r >> 2;
#pragma unroll
        for (int q = 0; q < 4; ++q) {
            float4 v = make_float4(cA[q][0], cA[q][1], cA[q][2], cA[q][3]);
            *(float4*)(ct + (size_t)(rowbase + q) * (NC * KSEL) + by * KSEL + rG * 4) = v;
        }
    }
    if (r == 0) {
#pragma unroll
        for (int q = 0; q < 4; ++q)
            cs[(size_t)(rowbase + q) * NC + by] = sE[q];
    }
}

// ---------- kernel 3: merge chunks per row ----------
__global__ void k_merge(const float* __restrict__ cs, const float* __restrict__ ct,
                        float* __restrict__ partials) {
    int w = threadIdx.x >> 6, l = threadIdx.x & 63;
    int row = blockIdx.x * 4 + w;

    // lse = log(sum of per-chunk exp-sums), stabilizer 0 (values bounded by e)
    float s = (l < NC) ? cs[(size_t)row * NC + l] : 0.f;
#pragma unroll
    for (int off = 32; off > 0; off >>= 1) s += __shfl_xor(s, off, 64);
    float lse = logf(s);

    // top-17 of the 256 candidates; iteration 0 extracts the diagonal (global
    // max of the candidate set) and is excluded from the sum.
    const float4* cp = (const float4*)(ct + (size_t)row * (NC * KSEL));
    float4 v = cp[l];
    float v0 = v.x, v1 = v.y, v2 = v.z, v3 = v.w;
    float topsum = 0.f;
    for (int it = 0; it < KSEL + 1; ++it) {
        float b = fmaxf(fmaxf(v0, v1), fmaxf(v2, v3));
        float bv = b; int bl = l;
#pragma unroll
        for (int off = 32; off > 0; off >>= 1) {
            float ov = __shfl_xor(bv, off, 64);
            int ol = __shfl_xor(bl, off, 64);
            if (ov > bv || (ov == bv && ol < bl)) { bv = ov; bl = ol; }
        }
        if (it > 0) topsum += bv;
        if (bl == l) {                       // remove exactly one instance
            if (v0 == bv)      v0 = NEG_INF_F;
            else if (v1 == bv) v1 = NEG_INF_F;
            else if (v2 == bv) v2 = NEG_INF_F;
            else               v3 = NEG_INF_F;
        }
    }
    if (l == 0) partials[row] = (float)KSEL * lse - topsum;
}

// ---------- kernel 4: deterministic final reduction ----------
__global__ void k_reduce(const float* __restrict__ partials, float* __restrict__ out) {
    __shared__ float sh[256];
    int tid = threadIdx.x;
    float s = 0.f;
    for (int i = tid; i < N; i += 256) s += partials[i];
    sh[tid] = s;
    __syncthreads();
    for (int st = 128; st > 0; st >>= 1) {
        if (tid < st) sh[tid] += sh[tid + st];
        __syncthreads();
    }
    if (tid == 0) out[0] = sh[0];
}

extern "C" void kernel_launch(void* const* d_in, const int* in_sizes, int n_in,
                              void* d_out, int out_size, void* d_ws, size_t ws_size,
                              hipStream_t stream) {
    const float* x = (const float*)d_in[0];
    float* out = (float*)d_out;

    unsigned short* xn = (unsigned short*)d_ws;                 // 2 MB
    float* cs = (float*)((char*)d_ws + (2u << 20));             // 512 KB
    float* ct = cs + (size_t)N * NC;                            // 8 MB
    float* partials = ct + (size_t)N * NC * KSEL;               // 32 KB

    k_normalize<<<N, 64, 0, stream>>>(x, xn);
    k_tiles<<<dim3(N / BM, NC), 256, 0, stream>>>(xn, cs, ct);
    k_merge<<<N / 4, 256, 0, stream>>>(cs, ct, partials);
    k_reduce<<<1, 256, 0, stream>>>(partials, out);
}

// Round 5
// 161.265 us; speedup vs baseline: 11.2952x; 1.0897x over previous
//
#include <hip/hip_runtime.h>
#include <math.h>

#define N 8192
#define D 128
#define KSEL 16
#define CH 512            // columns per chunk (per wave)
#define NC (N / CH)       // 16 chunks per row
#define BM 64             // rows per block (4 waves x 16)
#define NEG_INF_F (-1e30f)

typedef __attribute__((ext_vector_type(8))) short short8;
typedef __attribute__((ext_vector_type(4))) float f32x4;
typedef __attribute__((ext_vector_type(2))) unsigned short ush2;

static __device__ __forceinline__ unsigned short f2bf(float f) {
    unsigned u = __float_as_uint(f);
    u += 0x7FFF + ((u >> 16) & 1);          // RNE
    return (unsigned short)(u >> 16);
}

// branchless sorted top-4 insert (c0 >= c1 >= c2 >= c3)
static __device__ __forceinline__ void ins4(float& c0, float& c1, float& c2, float& c3, float f) {
    float m0 = fminf(c0, f);  c0 = fmaxf(c0, f);
    float m1 = fminf(c1, m0); c1 = fmaxf(c1, m0);
    float m2 = fminf(c2, m1); c2 = fmaxf(c2, m1);
    c3 = fmaxf(c3, m2);
}

// ---------- kernel 1: normalize rows, emit bf16 xn ----------
__global__ void k_normalize(const float* __restrict__ x, unsigned short* __restrict__ xn) {
    int row = blockIdx.x * 4 + (threadIdx.x >> 6);
    int lane = threadIdx.x & 63;
    const float2* x2 = (const float2*)(x + (size_t)row * D);
    float2 a = x2[lane];
    float s = fmaf(a.x, a.x, a.y * a.y);
#pragma unroll
    for (int off = 32; off > 0; off >>= 1) s += __shfl_xor(s, off, 64);
    float inv = rsqrtf(s);
    ush2 h;
    h.x = f2bf(a.x * inv);
    h.y = f2bf(a.y * inv);
    *(ush2*)(xn + (size_t)row * D + lane * 2) = h;
}

// ---------- kernel 2: MFMA + fused in-register epilogue, SW-pipelined ----------
// Lane (p,r) owns rows p*4+q (q=0..3) at cols {j0 + t*16 + r}.
// 2 tiles per step (independent MFMA chains), double-buffered B fragments:
// loads for step s+1 issue before the compute of step s (hides L2 latency).
// Diagonal stays IN exp-sum (reference keeps self) and IN candidates
// (S_ii ~ 1.0 is the candidate max; merge extracts top-17, drops the max).

#define LDTILE(dst, tile) {                                                     \
    const short8* _q = (const short8*)(bbase + (size_t)(tile) * (16 * D));      \
    dst[0] = _q[0]; dst[1] = _q[4]; dst[2] = _q[8]; dst[3] = _q[12]; }

#define COMP(bt0, bt1) {                                                        \
    f32x4 a0 = {0.f, 0.f, 0.f, 0.f}, a1 = {0.f, 0.f, 0.f, 0.f};                 \
    a0 = __builtin_amdgcn_mfma_f32_16x16x32_bf16(af0, bt0[0], a0, 0, 0, 0);     \
    a0 = __builtin_amdgcn_mfma_f32_16x16x32_bf16(af1, bt0[1], a0, 0, 0, 0);     \
    a0 = __builtin_amdgcn_mfma_f32_16x16x32_bf16(af2, bt0[2], a0, 0, 0, 0);     \
    a0 = __builtin_amdgcn_mfma_f32_16x16x32_bf16(af3, bt0[3], a0, 0, 0, 0);     \
    a1 = __builtin_amdgcn_mfma_f32_16x16x32_bf16(af0, bt1[0], a1, 0, 0, 0);     \
    a1 = __builtin_amdgcn_mfma_f32_16x16x32_bf16(af1, bt1[1], a1, 0, 0, 0);     \
    a1 = __builtin_amdgcn_mfma_f32_16x16x32_bf16(af2, bt1[2], a1, 0, 0, 0);     \
    a1 = __builtin_amdgcn_mfma_f32_16x16x32_bf16(af3, bt1[3], a1, 0, 0, 0);     \
    _Pragma("unroll")                                                           \
    for (int q = 0; q < 4; ++q) {                                               \
        float v = a0[q];                                                        \
        sE[q] += __expf(v);                                                     \
        ins4(cA[q][0], cA[q][1], cA[q][2], cA[q][3], v);                        \
        v = a1[q];                                                              \
        sE[q] += __expf(v);                                                     \
        ins4(cA[q][0], cA[q][1], cA[q][2], cA[q][3], v);                        \
    } }

__global__ __launch_bounds__(256, 4) void k_tiles(const unsigned short* __restrict__ xn,
                                                  float* __restrict__ cs,
                                                  float* __restrict__ ct) {
    const int tid = threadIdx.x;
    const int w = tid >> 6;
    const int l = tid & 63;
    const int r = l & 15;
    const int p = l >> 4;
    const int i0 = blockIdx.x * BM;
    const int j0 = blockIdx.y * CH;
    const int by = blockIdx.y;

    // A fragments
    const int arow = i0 + w * 16 + r;
    const unsigned short* ap = xn + (size_t)arow * D + p * 8;
    short8 af0 = *(const short8*)(ap);
    short8 af1 = *(const short8*)(ap + 32);
    short8 af2 = *(const short8*)(ap + 64);
    short8 af3 = *(const short8*)(ap + 96);

    float sE[4];
    float cA[4][4];
#pragma unroll
    for (int q = 0; q < 4; ++q) {
        sE[q] = 0.f;
        cA[q][0] = cA[q][1] = cA[q][2] = cA[q][3] = NEG_INF_F;
    }

    const unsigned short* bbase = xn + (size_t)(j0 + r) * D + p * 8;

    short8 bufA0[4], bufA1[4], bufB0[4], bufB1[4];
    LDTILE(bufA0, 0) LDTILE(bufA1, 1)

#pragma unroll
    for (int s = 0; s < 16; ++s) {
        if ((s & 1) == 0) {
            if (s < 15) { LDTILE(bufB0, 2 * s + 2) LDTILE(bufB1, 2 * s + 3) }
            COMP(bufA0, bufA1)
        } else {
            if (s < 15) { LDTILE(bufA0, 2 * s + 2) LDTILE(bufA1, 2 * s + 3) }
            COMP(bufB0, bufB1)
        }
    }

    // merge top-4 across 4-lane subgroups -> top-4 per 128-col stripe
#pragma unroll
    for (int o = 1; o <= 2; o <<= 1) {
#pragma unroll
        for (int q = 0; q < 4; ++q) {
            float o0 = __shfl_xor(cA[q][0], o, 64);
            float o1 = __shfl_xor(cA[q][1], o, 64);
            float o2 = __shfl_xor(cA[q][2], o, 64);
            float o3 = __shfl_xor(cA[q][3], o, 64);
            ins4(cA[q][0], cA[q][1], cA[q][2], cA[q][3], o0);
            ins4(cA[q][0], cA[q][1], cA[q][2], cA[q][3], o1);
            ins4(cA[q][0], cA[q][1], cA[q][2], cA[q][3], o2);
            ins4(cA[q][0], cA[q][1], cA[q][2], cA[q][3], o3);
        }
    }

    // full 16-lane exp-sum reduce (same p group)
#pragma unroll
    for (int o = 1; o <= 8; o <<= 1)
#pragma unroll
        for (int q = 0; q < 4; ++q)
            sE[q] += __shfl_xor(sE[q], o, 64);

    const int rowbase = i0 + w * 16 + p * 4;
    if ((r & 3) == 0) {
        int rG = r >> 2;
#pragma unroll
        for (int q = 0; q < 4; ++q) {
            float4 v = make_float4(cA[q][0], cA[q][1], cA[q][2], cA[q][3]);
            *(float4*)(ct + (size_t)(rowbase + q) * (NC * KSEL) + by * KSEL + rG * 4) = v;
        }
    }
    if (r == 0) {
#pragma unroll
        for (int q = 0; q < 4; ++q)
            cs[(size_t)(rowbase + q) * NC + by] = sE[q];
    }
}

// ---------- kernel 3: merge chunks per row ----------
__global__ void k_merge(const float* __restrict__ cs, const float* __restrict__ ct,
                        float* __restrict__ partials) {
    int w = threadIdx.x >> 6, l = threadIdx.x & 63;
    int row = blockIdx.x * 4 + w;

    // lse = log(sum of per-chunk exp-sums), stabilizer 0 (values bounded by e)
    float s = (l < NC) ? cs[(size_t)row * NC + l] : 0.f;
#pragma unroll
    for (int off = 32; off > 0; off >>= 1) s += __shfl_xor(s, off, 64);
    float lse = logf(s);

    // top-17 of the 256 candidates; iteration 0 extracts the diagonal (global
    // max of the candidate set) and is excluded from the sum.
    const float4* cp = (const float4*)(ct + (size_t)row * (NC * KSEL));
    float4 v = cp[l];
    float v0 = v.x, v1 = v.y, v2 = v.z, v3 = v.w;
    float topsum = 0.f;
    for (int it = 0; it < KSEL + 1; ++it) {
        float b = fmaxf(fmaxf(v0, v1), fmaxf(v2, v3));
        float bv = b; int bl = l;
#pragma unroll
        for (int off = 32; off > 0; off >>= 1) {
            float ov = __shfl_xor(bv, off, 64);
            int ol = __shfl_xor(bl, off, 64);
            if (ov > bv || (ov == bv && ol < bl)) { bv = ov; bl = ol; }
        }
        if (it > 0) topsum += bv;
        if (bl == l) {                       // remove exactly one instance
            if (v0 == bv)      v0 = NEG_INF_F;
            else if (v1 == bv) v1 = NEG_INF_F;
            else if (v2 == bv) v2 = NEG_INF_F;
            else               v3 = NEG_INF_F;
        }
    }
    if (l == 0) partials[row] = (float)KSEL * lse - topsum;
}

// ---------- kernel 4: deterministic final reduction ----------
__global__ void k_reduce(const float* __restrict__ partials, float* __restrict__ out) {
    __shared__ float sh[256];
    int tid = threadIdx.x;
    float s = 0.f;
    for (int i = tid; i < N; i += 256) s += partials[i];
    sh[tid] = s;
    __syncthreads();
    for (int st = 128; st > 0; st >>= 1) {
        if (tid < st) sh[tid] += sh[tid + st];
        __syncthreads();
    }
    if (tid == 0) out[0] = sh[0];
}

extern "C" void kernel_launch(void* const* d_in, const int* in_sizes, int n_in,
                              void* d_out, int out_size, void* d_ws, size_t ws_size,
                              hipStream_t stream) {
    const float* x = (const float*)d_in[0];
    float* out = (float*)d_out;

    unsigned short* xn = (unsigned short*)d_ws;                 // 2 MB
    float* cs = (float*)((char*)d_ws + (2u << 20));             // 512 KB
    float* ct = cs + (size_t)N * NC;                            // 8 MB
    float* partials = ct + (size_t)N * NC * KSEL;               // 32 KB

    k_normalize<<<N / 4, 256, 0, stream>>>(x, xn);
    k_tiles<<<dim3(N / BM, NC), 256, 0, stream>>>(xn, cs, ct);
    k_merge<<<N / 4, 256, 0, stream>>>(cs, ct, partials);
    k_reduce<<<1, 256, 0, stream>>>(partials, out);
}

// Round 6
// 89.165 us; speedup vs baseline: 20.4285x; 1.8086x over previous
//
#include <hip/hip_runtime.h>
#include <math.h>

#define N 8192
#define D 128
#define KSEL 16
#define CH 512            // columns per chunk (per block)
#define NC (N / CH)       // 16 chunks per row
#define BM 64             // rows per block (4 waves x 16)
#define PH (CH / 32)      // 16 phases, 2 16-col tiles per phase
#define NEG_INF_F (-1e30f)

typedef __attribute__((ext_vector_type(8))) short short8;
typedef __attribute__((ext_vector_type(4))) float f32x4;
typedef __attribute__((ext_vector_type(2))) unsigned short ush2;

static __device__ __forceinline__ unsigned short f2bf(float f) {
    unsigned u = __float_as_uint(f);
    u += 0x7FFF + ((u >> 16) & 1);          // RNE
    return (unsigned short)(u >> 16);
}

// branchless sorted top-4 insert (c0 >= c1 >= c2 >= c3)
static __device__ __forceinline__ void ins4(float& c0, float& c1, float& c2, float& c3, float f) {
    float m0 = fminf(c0, f);  c0 = fmaxf(c0, f);
    float m1 = fminf(c1, m0); c1 = fmaxf(c1, m0);
    float m2 = fminf(c2, m1); c2 = fmaxf(c2, m1);
    c3 = fmaxf(c3, m2);
}

// async global->LDS, 16B per lane, LDS dest = uniform base + lane*16
#define GLOAD_LDS(gsrc, ldst)                                                     \
    __builtin_amdgcn_global_load_lds(                                             \
        (const __attribute__((address_space(1))) unsigned int*)(const void*)(gsrc),\
        (__attribute__((address_space(3))) unsigned int*)(void*)(ldst), 16, 0, 0)

// ---------- kernel 1: normalize rows, emit bf16 xn ----------
__global__ void k_normalize(const float* __restrict__ x, unsigned short* __restrict__ xn) {
    int row = blockIdx.x * 4 + (threadIdx.x >> 6);
    int lane = threadIdx.x & 63;
    const float2* x2 = (const float2*)(x + (size_t)row * D);
    float2 a = x2[lane];
    float s = fmaf(a.x, a.x, a.y * a.y);
#pragma unroll
    for (int off = 32; off > 0; off >>= 1) s += __shfl_xor(s, off, 64);
    float inv = rsqrtf(s);
    ush2 h;
    h.x = f2bf(a.x * inv);
    h.y = f2bf(a.y * inv);
    *(ush2*)(xn + (size_t)row * D + lane * 2) = h;
}

// ---------- kernel 2: LDS-staged MFMA + fused in-register epilogue ----------
// B fragments staged via global_load_lds so that LDS slot l holds exactly the
// fragment lane l consumes: (col = l&15, k = (l>>4)*8 + slice*32). Reads are
// ds_read_b128 at base + 16*l -> linear, conflict-free, shared by all 4 waves.
// Double-buffered: stage phase p+1 (async DMA) before computing phase p; the
// compiler's vmcnt(0)+s_barrier drain at __syncthreads publishes the slices.
// Diagonal stays IN exp-sum (reference keeps self) and IN candidates
// (S_ii ~ 1.0 is the candidate max; merge extracts top-17, drops the max).
__global__ __launch_bounds__(256, 4) void k_tiles(const unsigned short* __restrict__ xn,
                                                  float* __restrict__ cs,
                                                  float* __restrict__ ct) {
    // [buf][tile][slice][lane][8 bf16] = 16 KB
    __shared__ unsigned short Bsh[2][2][4][64][8];

    const int tid = threadIdx.x;
    const int w = tid >> 6;
    const int l = tid & 63;
    const int r = l & 15;
    const int p = l >> 4;
    const int i0 = blockIdx.x * BM;
    const int j0 = blockIdx.y * CH;
    const int by = blockIdx.y;

    // A fragments: lane (p,r) holds row i0+w*16+r, k = p*8 + slice*32
    const int arow = i0 + w * 16 + r;
    const unsigned short* ap = xn + (size_t)arow * D + p * 8;
    short8 af0 = *(const short8*)(ap);
    short8 af1 = *(const short8*)(ap + 32);
    short8 af2 = *(const short8*)(ap + 64);
    short8 af3 = *(const short8*)(ap + 96);

    float sE[4];
    float cA[4][4];
#pragma unroll
    for (int q = 0; q < 4; ++q) {
        sE[q] = 0.f;
        cA[q][0] = cA[q][1] = cA[q][2] = cA[q][3] = NEG_INF_F;
    }

    // per-lane staging source: wave w stages slice w of both tiles of a phase
    // lane l fetches B[row = j0 + ph*32 + tile*16 + (l&15)][k = (l>>4)*8 + w*32]
    const unsigned short* sbase = xn + (size_t)(j0 + r) * D + p * 8 + w * 32;

    // prologue: stage phase 0 into buf 0
    GLOAD_LDS(sbase,           &Bsh[0][0][w][0][0]);
    GLOAD_LDS(sbase + 16 * D,  &Bsh[0][1][w][0][0]);
    __syncthreads();

    for (int ph = 0; ph < PH; ++ph) {
        const int buf = ph & 1;
        if (ph < PH - 1) {
            const unsigned short* s1 = sbase + (size_t)(ph + 1) * (32 * D);
            GLOAD_LDS(s1,          &Bsh[buf ^ 1][0][w][0][0]);
            GLOAD_LDS(s1 + 16 * D, &Bsh[buf ^ 1][1][w][0][0]);
        }
#pragma unroll
        for (int tt = 0; tt < 2; ++tt) {
            short8 b0 = *(const short8*)&Bsh[buf][tt][0][l][0];
            short8 b1 = *(const short8*)&Bsh[buf][tt][1][l][0];
            short8 b2 = *(const short8*)&Bsh[buf][tt][2][l][0];
            short8 b3 = *(const short8*)&Bsh[buf][tt][3][l][0];
            f32x4 acc = {0.f, 0.f, 0.f, 0.f};
            acc = __builtin_amdgcn_mfma_f32_16x16x32_bf16(af0, b0, acc, 0, 0, 0);
            acc = __builtin_amdgcn_mfma_f32_16x16x32_bf16(af1, b1, acc, 0, 0, 0);
            acc = __builtin_amdgcn_mfma_f32_16x16x32_bf16(af2, b2, acc, 0, 0, 0);
            acc = __builtin_amdgcn_mfma_f32_16x16x32_bf16(af3, b3, acc, 0, 0, 0);
#pragma unroll
            for (int q = 0; q < 4; ++q) {
                float v = acc[q];
                sE[q] += __expf(v);
                ins4(cA[q][0], cA[q][1], cA[q][2], cA[q][3], v);
            }
        }
        __syncthreads();
    }

    // merge top-4 across 4-lane subgroups -> top-4 per 128-col stripe
#pragma unroll
    for (int o = 1; o <= 2; o <<= 1) {
#pragma unroll
        for (int q = 0; q < 4; ++q) {
            float o0 = __shfl_xor(cA[q][0], o, 64);
            float o1 = __shfl_xor(cA[q][1], o, 64);
            float o2 = __shfl_xor(cA[q][2], o, 64);
            float o3 = __shfl_xor(cA[q][3], o, 64);
            ins4(cA[q][0], cA[q][1], cA[q][2], cA[q][3], o0);
            ins4(cA[q][0], cA[q][1], cA[q][2], cA[q][3], o1);
            ins4(cA[q][0], cA[q][1], cA[q][2], cA[q][3], o2);
            ins4(cA[q][0], cA[q][1], cA[q][2], cA[q][3], o3);
        }
    }

    // full 16-lane exp-sum reduce (same p group)
#pragma unroll
    for (int o = 1; o <= 8; o <<= 1)
#pragma unroll
        for (int q = 0; q < 4; ++q)
            sE[q] += __shfl_xor(sE[q], o, 64);

    const int rowbase = i0 + w * 16 + p * 4;
    if ((r & 3) == 0) {
        int rG = r >> 2;
#pragma unroll
        for (int q = 0; q < 4; ++q) {
            float4 v = make_float4(cA[q][0], cA[q][1], cA[q][2], cA[q][3]);
            *(float4*)(ct + (size_t)(rowbase + q) * (NC * KSEL) + by * KSEL + rG * 4) = v;
        }
    }
    if (r == 0) {
#pragma unroll
        for (int q = 0; q < 4; ++q)
            cs[(size_t)(rowbase + q) * NC + by] = sE[q];
    }
}

// ---------- kernel 3: merge chunks per row ----------
__global__ void k_merge(const float* __restrict__ cs, const float* __restrict__ ct,
                        float* __restrict__ partials) {
    int w = threadIdx.x >> 6, l = threadIdx.x & 63;
    int row = blockIdx.x * 4 + w;

    // lse = log(sum of per-chunk exp-sums), stabilizer 0 (values bounded by e)
    float s = (l < NC) ? cs[(size_t)row * NC + l] : 0.f;
#pragma unroll
    for (int off = 32; off > 0; off >>= 1) s += __shfl_xor(s, off, 64);
    float lse = logf(s);

    // top-17 of the 256 candidates; iteration 0 extracts the diagonal (global
    // max of the candidate set) and is excluded from the sum.
    const float4* cp = (const float4*)(ct + (size_t)row * (NC * KSEL));
    float4 v = cp[l];
    float v0 = v.x, v1 = v.y, v2 = v.z, v3 = v.w;
    float topsum = 0.f;
    for (int it = 0; it < KSEL + 1; ++it) {
        float b = fmaxf(fmaxf(v0, v1), fmaxf(v2, v3));
        float bv = b; int bl = l;
#pragma unroll
        for (int off = 32; off > 0; off >>= 1) {
            float ov = __shfl_xor(bv, off, 64);
            int ol = __shfl_xor(bl, off, 64);
            if (ov > bv || (ov == bv && ol < bl)) { bv = ov; bl = ol; }
        }
        if (it > 0) topsum += bv;
        if (bl == l) {                       // remove exactly one instance
            if (v0 == bv)      v0 = NEG_INF_F;
            else if (v1 == bv) v1 = NEG_INF_F;
            else if (v2 == bv) v2 = NEG_INF_F;
            else               v3 = NEG_INF_F;
        }
    }
    if (l == 0) partials[row] = (float)KSEL * lse - topsum;
}

// ---------- kernel 4: deterministic final reduction ----------
__global__ void k_reduce(const float* __restrict__ partials, float* __restrict__ out) {
    __shared__ float sh[256];
    int tid = threadIdx.x;
    float s = 0.f;
    for (int i = tid; i < N; i += 256) s += partials[i];
    sh[tid] = s;
    __syncthreads();
    for (int st = 128; st > 0; st >>= 1) {
        if (tid < st) sh[tid] += sh[tid + st];
        __syncthreads();
    }
    if (tid == 0) out[0] = sh[0];
}

extern "C" void kernel_launch(void* const* d_in, const int* in_sizes, int n_in,
                              void* d_out, int out_size, void* d_ws, size_t ws_size,
                              hipStream_t stream) {
    const float* x = (const float*)d_in[0];
    float* out = (float*)d_out;

    unsigned short* xn = (unsigned short*)d_ws;                 // 2 MB
    float* cs = (float*)((char*)d_ws + (2u << 20));             // 512 KB
    float* ct = cs + (size_t)N * NC;                            // 8 MB
    float* partials = ct + (size_t)N * NC * KSEL;               // 32 KB

    k_normalize<<<N / 4, 256, 0, stream>>>(x, xn);
    k_tiles<<<dim3(N / BM, NC), 256, 0, stream>>>(xn, cs, ct);
    k_merge<<<N / 4, 256, 0, stream>>>(cs, ct, partials);
    k_reduce<<<1, 256, 0, stream>>>(partials, out);
}

// Round 7
// 88.380 us; speedup vs baseline: 20.6102x; 1.0089x over previous
//
#include <hip/hip_runtime.h>
#include <math.h>

#define N 8192
#define D 128
#define KSEL 16
#define CH 512            // columns per chunk (per block)
#define NC (N / CH)       // 16 chunks per row
#define BM 64             // rows per block (4 waves x 16)
#define PH (CH / 32)      // 16 phases, 2 16-col tiles per phase
#define NEG_INF_F (-1e30f)
#define LOG2E 1.44269504f
#define LN2 0.69314718f

typedef __attribute__((ext_vector_type(8))) short short8;
typedef __attribute__((ext_vector_type(4))) float f32x4;
typedef __attribute__((ext_vector_type(2))) unsigned short ush2;

static __device__ __forceinline__ unsigned short f2bf(float f) {
    unsigned u = __float_as_uint(f);
    u += 0x7FFF + ((u >> 16) & 1);          // RNE
    return (unsigned short)(u >> 16);
}

// branchless sorted top-4 insert (c0 >= c1 >= c2 >= c3)
static __device__ __forceinline__ void ins4(float& c0, float& c1, float& c2, float& c3, float f) {
    float m0 = fminf(c0, f);  c0 = fmaxf(c0, f);
    float m1 = fminf(c1, m0); c1 = fmaxf(c1, m0);
    float m2 = fminf(c2, m1); c2 = fmaxf(c2, m1);
    c3 = fmaxf(c3, m2);
}

// async global->LDS, 16B per lane, LDS dest = uniform base + lane*16
#define GLOAD_LDS(gsrc, ldst)                                                     \
    __builtin_amdgcn_global_load_lds(                                             \
        (const __attribute__((address_space(1))) unsigned int*)(const void*)(gsrc),\
        (__attribute__((address_space(3))) unsigned int*)(void*)(ldst), 16, 0, 0)

// ---------- kernel 1: normalize rows; xnB = bf16(xn), xnA = bf16(log2e * xn) ----------
__global__ void k_normalize(const float* __restrict__ x,
                            unsigned short* __restrict__ xnA,
                            unsigned short* __restrict__ xnB) {
    int row = blockIdx.x * 4 + (threadIdx.x >> 6);
    int lane = threadIdx.x & 63;
    const float2* x2 = (const float2*)(x + (size_t)row * D);
    float2 a = x2[lane];
    float s = fmaf(a.x, a.x, a.y * a.y);
#pragma unroll
    for (int off = 32; off > 0; off >>= 1) s += __shfl_xor(s, off, 64);
    float inv = rsqrtf(s);
    ush2 hb, ha;
    hb.x = f2bf(a.x * inv);
    hb.y = f2bf(a.y * inv);
    ha.x = f2bf(a.x * inv * LOG2E);
    ha.y = f2bf(a.y * inv * LOG2E);
    *(ush2*)(xnB + (size_t)row * D + lane * 2) = hb;
    *(ush2*)(xnA + (size_t)row * D + lane * 2) = ha;
}

// ---------- kernel 2: LDS-staged MFMA + fused in-register epilogue ----------
// A-operand is pre-scaled by log2(e), so acc = log2e * S: exp-sum is a bare
// exp2 (1 op) and top-k ordering is unchanged (monotone scaling; merge
// multiplies topsum by ln2). Per-element epilogue: exp2 + add + top-2 insert
// (3 min/max) = 5 VALU ops.
// B fragments staged via global_load_lds so LDS slot l holds exactly the
// fragment lane l consumes; reads are linear ds_read_b128, conflict-free,
// shared by all 4 waves. Double-buffered across phases.
// Diagonal stays IN exp-sum (reference keeps self) and IN candidates
// (scaled S_ii ~ 1.44 is the candidate max; merge extracts top-17, drops max).
__global__ __launch_bounds__(256, 6) void k_tiles(const unsigned short* __restrict__ xnA,
                                                  const unsigned short* __restrict__ xnB,
                                                  float* __restrict__ cs,
                                                  float* __restrict__ ct) {
    // [buf][tile][slice][lane][8 bf16] = 16 KB
    __shared__ unsigned short Bsh[2][2][4][64][8];

    const int tid = threadIdx.x;
    const int w = tid >> 6;
    const int l = tid & 63;
    const int r = l & 15;
    const int p = l >> 4;
    const int i0 = blockIdx.x * BM;
    const int j0 = blockIdx.y * CH;
    const int by = blockIdx.y;

    // A fragments (scaled): lane (p,r) holds row i0+w*16+r, k = p*8 + slice*32
    const int arow = i0 + w * 16 + r;
    const unsigned short* ap = xnA + (size_t)arow * D + p * 8;
    short8 af0 = *(const short8*)(ap);
    short8 af1 = *(const short8*)(ap + 32);
    short8 af2 = *(const short8*)(ap + 64);
    short8 af3 = *(const short8*)(ap + 96);

    float sE[4], c0[4], c1[4];
#pragma unroll
    for (int q = 0; q < 4; ++q) {
        sE[q] = 0.f;
        c0[q] = c1[q] = NEG_INF_F;
    }

    // per-lane staging source: wave w stages slice w of both tiles of a phase
    const unsigned short* sbase = xnB + (size_t)(j0 + r) * D + p * 8 + w * 32;

    // prologue: stage phase 0 into buf 0
    GLOAD_LDS(sbase,           &Bsh[0][0][w][0][0]);
    GLOAD_LDS(sbase + 16 * D,  &Bsh[0][1][w][0][0]);
    __syncthreads();

    for (int ph = 0; ph < PH; ++ph) {
        const int buf = ph & 1;
        if (ph < PH - 1) {
            const unsigned short* s1 = sbase + (size_t)(ph + 1) * (32 * D);
            GLOAD_LDS(s1,          &Bsh[buf ^ 1][0][w][0][0]);
            GLOAD_LDS(s1 + 16 * D, &Bsh[buf ^ 1][1][w][0][0]);
        }
#pragma unroll
        for (int tt = 0; tt < 2; ++tt) {
            short8 b0 = *(const short8*)&Bsh[buf][tt][0][l][0];
            short8 b1 = *(const short8*)&Bsh[buf][tt][1][l][0];
            short8 b2 = *(const short8*)&Bsh[buf][tt][2][l][0];
            short8 b3 = *(const short8*)&Bsh[buf][tt][3][l][0];
            f32x4 acc = {0.f, 0.f, 0.f, 0.f};
            acc = __builtin_amdgcn_mfma_f32_16x16x32_bf16(af0, b0, acc, 0, 0, 0);
            acc = __builtin_amdgcn_mfma_f32_16x16x32_bf16(af1, b1, acc, 0, 0, 0);
            acc = __builtin_amdgcn_mfma_f32_16x16x32_bf16(af2, b2, acc, 0, 0, 0);
            acc = __builtin_amdgcn_mfma_f32_16x16x32_bf16(af3, b3, acc, 0, 0, 0);
#pragma unroll
            for (int q = 0; q < 4; ++q) {
                float v = acc[q];
                sE[q] += __builtin_exp2f(v);
                float m0 = fminf(c0[q], v);     // top-2 insert, 3 ops
                c0[q] = fmaxf(c0[q], v);
                c1[q] = fmaxf(c1[q], m0);
            }
        }
        __syncthreads();
    }

    // expand to top-4 and merge across 4-lane subgroups -> top-4 per 128 cols
    float cA[4][4];
#pragma unroll
    for (int q = 0; q < 4; ++q) {
        cA[q][0] = c0[q]; cA[q][1] = c1[q];
        cA[q][2] = NEG_INF_F; cA[q][3] = NEG_INF_F;
    }
#pragma unroll
    for (int o = 1; o <= 2; o <<= 1) {
#pragma unroll
        for (int q = 0; q < 4; ++q) {
            float o0 = __shfl_xor(cA[q][0], o, 64);
            float o1 = __shfl_xor(cA[q][1], o, 64);
            float o2 = __shfl_xor(cA[q][2], o, 64);
            float o3 = __shfl_xor(cA[q][3], o, 64);
            ins4(cA[q][0], cA[q][1], cA[q][2], cA[q][3], o0);
            ins4(cA[q][0], cA[q][1], cA[q][2], cA[q][3], o1);
            ins4(cA[q][0], cA[q][1], cA[q][2], cA[q][3], o2);
            ins4(cA[q][0], cA[q][1], cA[q][2], cA[q][3], o3);
        }
    }

    // full 16-lane exp-sum reduce (same p group)
#pragma unroll
    for (int o = 1; o <= 8; o <<= 1)
#pragma unroll
        for (int q = 0; q < 4; ++q)
            sE[q] += __shfl_xor(sE[q], o, 64);

    const int rowbase = i0 + w * 16 + p * 4;
    if ((r & 3) == 0) {
        int rG = r >> 2;
#pragma unroll
        for (int q = 0; q < 4; ++q) {
            float4 v = make_float4(cA[q][0], cA[q][1], cA[q][2], cA[q][3]);
            *(float4*)(ct + (size_t)(rowbase + q) * (NC * KSEL) + by * KSEL + rG * 4) = v;
        }
    }
    if (r == 0) {
#pragma unroll
        for (int q = 0; q < 4; ++q)
            cs[(size_t)(rowbase + q) * NC + by] = sE[q];
    }
}

// ---------- kernel 3: merge chunks per row ----------
__global__ void k_merge(const float* __restrict__ cs, const float* __restrict__ ct,
                        float* __restrict__ partials) {
    int w = threadIdx.x >> 6, l = threadIdx.x & 63;
    int row = blockIdx.x * 4 + w;

    // lse = log(sum of per-chunk exp-sums); values bounded (2^acc <= 2.72)
    float s = (l < NC) ? cs[(size_t)row * NC + l] : 0.f;
#pragma unroll
    for (int off = 32; off > 0; off >>= 1) s += __shfl_xor(s, off, 64);
    float lse = logf(s);

    // top-17 of the 256 candidates (scaled by log2e); iteration 0 extracts the
    // diagonal (global max of the candidate set) and is excluded from the sum.
    const float4* cp = (const float4*)(ct + (size_t)row * (NC * KSEL));
    float4 v = cp[l];
    float v0 = v.x, v1 = v.y, v2 = v.z, v3 = v.w;
    float topsum = 0.f;
    for (int it = 0; it < KSEL + 1; ++it) {
        float b = fmaxf(fmaxf(v0, v1), fmaxf(v2, v3));
        float bv = b; int bl = l;
#pragma unroll
        for (int off = 32; off > 0; off >>= 1) {
            float ov = __shfl_xor(bv, off, 64);
            int ol = __shfl_xor(bl, off, 64);
            if (ov > bv || (ov == bv && ol < bl)) { bv = ov; bl = ol; }
        }
        if (it > 0) topsum += bv;
        if (bl == l) {                       // remove exactly one instance
            if (v0 == bv)      v0 = NEG_INF_F;
            else if (v1 == bv) v1 = NEG_INF_F;
            else if (v2 == bv) v2 = NEG_INF_F;
            else               v3 = NEG_INF_F;
        }
    }
    if (l == 0) partials[row] = (float)KSEL * lse - LN2 * topsum;
}

// ---------- kernel 4: deterministic final reduction ----------
__global__ void k_reduce(const float* __restrict__ partials, float* __restrict__ out) {
    __shared__ float sh[256];
    int tid = threadIdx.x;
    float s = 0.f;
    for (int i = tid; i < N; i += 256) s += partials[i];
    sh[tid] = s;
    __syncthreads();
    for (int st = 128; st > 0; st >>= 1) {
        if (tid < st) sh[tid] += sh[tid + st];
        __syncthreads();
    }
    if (tid == 0) out[0] = sh[0];
}

extern "C" void kernel_launch(void* const* d_in, const int* in_sizes, int n_in,
                              void* d_out, int out_size, void* d_ws, size_t ws_size,
                              hipStream_t stream) {
    const float* x = (const float*)d_in[0];
    float* out = (float*)d_out;

    unsigned short* xnA = (unsigned short*)d_ws;                // 2 MB (scaled)
    unsigned short* xnB = xnA + (size_t)N * D;                  // 2 MB
    float* cs = (float*)((char*)d_ws + (4u << 20));             // 512 KB
    float* ct = cs + (size_t)N * NC;                            // 8 MB
    float* partials = ct + (size_t)N * NC * KSEL;               // 32 KB

    k_normalize<<<N / 4, 256, 0, stream>>>(x, xnA, xnB);
    k_tiles<<<dim3(N / BM, NC), 256, 0, stream>>>(xnA, xnB, cs, ct);
    k_merge<<<N / 4, 256, 0, stream>>>(cs, ct, partials);
    k_reduce<<<1, 256, 0, stream>>>(partials, out);
}

// Round 8
// 81.020 us; speedup vs baseline: 22.4824x; 1.0908x over previous
//
#include <hip/hip_runtime.h>
#include <math.h>

#define N 8192
#define D 128
#define KSEL 16
#define CH 512            // columns per chunk (per block)
#define NC (N / CH)       // 16 chunks per row
#define BM 128            // rows per block (4 waves x 2 sets x 16)
#define PH 8              // phases per chunk, 64 cols each
#define NEG_INF_F (-1e30f)
#define LOG2E 1.44269504f
#define LN2 0.69314718f

typedef __attribute__((ext_vector_type(8))) short short8;
typedef __attribute__((ext_vector_type(4))) float f32x4;
typedef __attribute__((ext_vector_type(2))) unsigned short ush2;

static __device__ __forceinline__ unsigned short f2bf(float f) {
    unsigned u = __float_as_uint(f);
    u += 0x7FFF + ((u >> 16) & 1);          // RNE
    return (unsigned short)(u >> 16);
}

// branchless sorted top-4 insert (c0 >= c1 >= c2 >= c3)
static __device__ __forceinline__ void ins4(float& c0, float& c1, float& c2, float& c3, float f) {
    float m0 = fminf(c0, f);  c0 = fmaxf(c0, f);
    float m1 = fminf(c1, m0); c1 = fmaxf(c1, m0);
    float m2 = fminf(c2, m1); c2 = fmaxf(c2, m1);
    c3 = fmaxf(c3, m2);
}

// async global->LDS, 16B per lane, LDS dest = uniform base + lane*16
#define GLOAD_LDS(gsrc, ldst)                                                     \
    __builtin_amdgcn_global_load_lds(                                             \
        (const __attribute__((address_space(1))) unsigned int*)(const void*)(gsrc),\
        (__attribute__((address_space(3))) unsigned int*)(void*)(ldst), 16, 0, 0)

// ---------- kernel 1: normalize rows; xnB = bf16(xn), xnA = bf16(log2e * xn) ----------
__global__ void k_normalize(const float* __restrict__ x,
                            unsigned short* __restrict__ xnA,
                            unsigned short* __restrict__ xnB) {
    int row = blockIdx.x * 4 + (threadIdx.x >> 6);
    int lane = threadIdx.x & 63;
    const float2* x2 = (const float2*)(x + (size_t)row * D);
    float2 a = x2[lane];
    float s = fmaf(a.x, a.x, a.y * a.y);
#pragma unroll
    for (int off = 32; off > 0; off >>= 1) s += __shfl_xor(s, off, 64);
    float inv = rsqrtf(s);
    ush2 hb, ha;
    hb.x = f2bf(a.x * inv);
    hb.y = f2bf(a.y * inv);
    ha.x = f2bf(a.x * inv * LOG2E);
    ha.y = f2bf(a.y * inv * LOG2E);
    *(ush2*)(xnB + (size_t)row * D + lane * 2) = hb;
    *(ush2*)(xnA + (size_t)row * D + lane * 2) = ha;
}

// ---------- kernel 2: LDS-staged MFMA, 2 A-row-sets per wave ----------
// Each B fragment (one ds_read_b128) feeds TWO MFMAs (row-sets at +0 and +64),
// halving LDS-port traffic per output vs round 7. A-operand pre-scaled by
// log2(e): acc = log2e * S, exp-sum is bare exp2, top-k order unchanged
// (merge multiplies topsum by ln2). Phases of 64 cols (4 tiles), double-
// buffered via global_load_lds with LDS slot = consuming lane index.
// Diagonal stays IN exp-sum (reference keeps self) and IN candidates
// (scaled S_ii ~ 1.44 is the candidate max; merge extracts top-17, drops max).
__global__ __launch_bounds__(256, 4) void k_tiles(const unsigned short* __restrict__ xnA,
                                                  const unsigned short* __restrict__ xnB,
                                                  float* __restrict__ cs,
                                                  float* __restrict__ ct) {
    // [buf][tile][slice][lane][8 bf16] = 32 KB
    __shared__ unsigned short Bsh[2][4][4][64][8];

    const int tid = threadIdx.x;
    const int w = tid >> 6;
    const int l = tid & 63;
    const int r = l & 15;                    // col-within-tile / A-row lane
    const int p = l >> 4;                    // k-group; output rows p*4+q
    const int i0 = blockIdx.x * BM;
    const int j0 = blockIdx.y * CH;
    const int by = blockIdx.y;

    // A fragments, two row-sets: rows i0 + set*64 + w*16 + r
    const unsigned short* ap = xnA + (size_t)(i0 + w * 16 + r) * D + p * 8;
    short8 af0 = *(const short8*)(ap);
    short8 af1 = *(const short8*)(ap + 32);
    short8 af2 = *(const short8*)(ap + 64);
    short8 af3 = *(const short8*)(ap + 96);
    const unsigned short* gp = ap + (size_t)64 * D;
    short8 ag0 = *(const short8*)(gp);
    short8 ag1 = *(const short8*)(gp + 32);
    short8 ag2 = *(const short8*)(gp + 64);
    short8 ag3 = *(const short8*)(gp + 96);

    float sE[2][4], c0[2][4], c1[2][4];
#pragma unroll
    for (int s2 = 0; s2 < 2; ++s2)
#pragma unroll
        for (int q = 0; q < 4; ++q) {
            sE[s2][q] = 0.f;
            c0[s2][q] = c1[s2][q] = NEG_INF_F;
        }

    // staging source: wave w stages slice w; lane l fetches
    // B[j0 + ph*64 + tile*16 + (l&15)][k = (l>>4)*8 + w*32]
    const unsigned short* sbase = xnB + (size_t)(j0 + r) * D + p * 8 + w * 32;

    // prologue: stage phase 0 into buf 0
#pragma unroll
    for (int tt = 0; tt < 4; ++tt)
        GLOAD_LDS(sbase + (size_t)tt * (16 * D), &Bsh[0][tt][w][0][0]);
    __syncthreads();

    for (int ph = 0; ph < PH; ++ph) {
        const int buf = ph & 1;
        if (ph < PH - 1) {
            const unsigned short* s1 = sbase + (size_t)(ph + 1) * (64 * D);
#pragma unroll
            for (int tt = 0; tt < 4; ++tt)
                GLOAD_LDS(s1 + (size_t)tt * (16 * D), &Bsh[buf ^ 1][tt][w][0][0]);
        }
#pragma unroll
        for (int tt = 0; tt < 4; ++tt) {
            short8 b0 = *(const short8*)&Bsh[buf][tt][0][l][0];
            short8 b1 = *(const short8*)&Bsh[buf][tt][1][l][0];
            short8 b2 = *(const short8*)&Bsh[buf][tt][2][l][0];
            short8 b3 = *(const short8*)&Bsh[buf][tt][3][l][0];
            f32x4 a0 = {0.f, 0.f, 0.f, 0.f};
            f32x4 a1 = {0.f, 0.f, 0.f, 0.f};
            a0 = __builtin_amdgcn_mfma_f32_16x16x32_bf16(af0, b0, a0, 0, 0, 0);
            a0 = __builtin_amdgcn_mfma_f32_16x16x32_bf16(af1, b1, a0, 0, 0, 0);
            a0 = __builtin_amdgcn_mfma_f32_16x16x32_bf16(af2, b2, a0, 0, 0, 0);
            a0 = __builtin_amdgcn_mfma_f32_16x16x32_bf16(af3, b3, a0, 0, 0, 0);
            a1 = __builtin_amdgcn_mfma_f32_16x16x32_bf16(ag0, b0, a1, 0, 0, 0);
            a1 = __builtin_amdgcn_mfma_f32_16x16x32_bf16(ag1, b1, a1, 0, 0, 0);
            a1 = __builtin_amdgcn_mfma_f32_16x16x32_bf16(ag2, b2, a1, 0, 0, 0);
            a1 = __builtin_amdgcn_mfma_f32_16x16x32_bf16(ag3, b3, a1, 0, 0, 0);
#pragma unroll
            for (int q = 0; q < 4; ++q) {
                float v = a0[q];
                sE[0][q] += __builtin_exp2f(v);
                float m0 = fminf(c0[0][q], v);
                c0[0][q] = fmaxf(c0[0][q], v);
                c1[0][q] = fmaxf(c1[0][q], m0);
                v = a1[q];
                sE[1][q] += __builtin_exp2f(v);
                m0 = fminf(c0[1][q], v);
                c0[1][q] = fmaxf(c0[1][q], v);
                c1[1][q] = fmaxf(c1[1][q], m0);
            }
        }
        __syncthreads();
    }

    // per row-set: expand to top-4, merge across 4-lane subgroups, reduce sE
#pragma unroll
    for (int s2 = 0; s2 < 2; ++s2) {
        float cA[4][4];
#pragma unroll
        for (int q = 0; q < 4; ++q) {
            cA[q][0] = c0[s2][q]; cA[q][1] = c1[s2][q];
            cA[q][2] = NEG_INF_F; cA[q][3] = NEG_INF_F;
        }
#pragma unroll
        for (int o = 1; o <= 2; o <<= 1) {
#pragma unroll
            for (int q = 0; q < 4; ++q) {
                float o0 = __shfl_xor(cA[q][0], o, 64);
                float o1 = __shfl_xor(cA[q][1], o, 64);
                float o2 = __shfl_xor(cA[q][2], o, 64);
                float o3 = __shfl_xor(cA[q][3], o, 64);
                ins4(cA[q][0], cA[q][1], cA[q][2], cA[q][3], o0);
                ins4(cA[q][0], cA[q][1], cA[q][2], cA[q][3], o1);
                ins4(cA[q][0], cA[q][1], cA[q][2], cA[q][3], o2);
                ins4(cA[q][0], cA[q][1], cA[q][2], cA[q][3], o3);
            }
        }
#pragma unroll
        for (int o = 1; o <= 8; o <<= 1)
#pragma unroll
            for (int q = 0; q < 4; ++q)
                sE[s2][q] += __shfl_xor(sE[s2][q], o, 64);

        const int rowbase = i0 + s2 * 64 + w * 16 + p * 4;
        if ((r & 3) == 0) {
            int rG = r >> 2;
#pragma unroll
            for (int q = 0; q < 4; ++q) {
                float4 v = make_float4(cA[q][0], cA[q][1], cA[q][2], cA[q][3]);
                *(float4*)(ct + (size_t)(rowbase + q) * (NC * KSEL) + by * KSEL + rG * 4) = v;
            }
        }
        if (r == 0) {
#pragma unroll
            for (int q = 0; q < 4; ++q)
                cs[(size_t)(rowbase + q) * NC + by] = sE[s2][q];
        }
    }
}

// ---------- kernel 3: merge chunks per row ----------
__global__ void k_merge(const float* __restrict__ cs, const float* __restrict__ ct,
                        float* __restrict__ partials) {
    int w = threadIdx.x >> 6, l = threadIdx.x & 63;
    int row = blockIdx.x * 4 + w;

    // lse = log(sum of per-chunk exp-sums); values bounded (2^acc <= 2.72)
    float s = (l < NC) ? cs[(size_t)row * NC + l] : 0.f;
#pragma unroll
    for (int off = 32; off > 0; off >>= 1) s += __shfl_xor(s, off, 64);
    float lse = logf(s);

    // top-17 of the 256 candidates (scaled by log2e); iteration 0 extracts the
    // diagonal (global max of the candidate set) and is excluded from the sum.
    const float4* cp = (const float4*)(ct + (size_t)row * (NC * KSEL));
    float4 v = cp[l];
    float v0 = v.x, v1 = v.y, v2 = v.z, v3 = v.w;
    float topsum = 0.f;
    for (int it = 0; it < KSEL + 1; ++it) {
        float b = fmaxf(fmaxf(v0, v1), fmaxf(v2, v3));
        float bv = b; int bl = l;
#pragma unroll
        for (int off = 32; off > 0; off >>= 1) {
            float ov = __shfl_xor(bv, off, 64);
            int ol = __shfl_xor(bl, off, 64);
            if (ov > bv || (ov == bv && ol < bl)) { bv = ov; bl = ol; }
        }
        if (it > 0) topsum += bv;
        if (bl == l) {                       // remove exactly one instance
            if (v0 == bv)      v0 = NEG_INF_F;
            else if (v1 == bv) v1 = NEG_INF_F;
            else if (v2 == bv) v2 = NEG_INF_F;
            else               v3 = NEG_INF_F;
        }
    }
    if (l == 0) partials[row] = (float)KSEL * lse - LN2 * topsum;
}

// ---------- kernel 4: deterministic final reduction ----------
__global__ void k_reduce(const float* __restrict__ partials, float* __restrict__ out) {
    __shared__ float sh[256];
    int tid = threadIdx.x;
    float s = 0.f;
    for (int i = tid; i < N; i += 256) s += partials[i];
    sh[tid] = s;
    __syncthreads();
    for (int st = 128; st > 0; st >>= 1) {
        if (tid < st) sh[tid] += sh[tid + st];
        __syncthreads();
    }
    if (tid == 0) out[0] = sh[0];
}

extern "C" void kernel_launch(void* const* d_in, const int* in_sizes, int n_in,
                              void* d_out, int out_size, void* d_ws, size_t ws_size,
                              hipStream_t stream) {
    const float* x = (const float*)d_in[0];
    float* out = (float*)d_out;

    unsigned short* xnA = (unsigned short*)d_ws;                // 2 MB (scaled)
    unsigned short* xnB = xnA + (size_t)N * D;                  // 2 MB
    float* cs = (float*)((char*)d_ws + (4u << 20));             // 512 KB
    float* ct = cs + (size_t)N * NC;                            // 8 MB
    float* partials = ct + (size_t)N * NC * KSEL;               // 32 KB

    k_normalize<<<N / 4, 256, 0, stream>>>(x, xnA, xnB);
    k_tiles<<<dim3(N / BM, NC), 256, 0, stream>>>(xnA, xnB, cs, ct);
    k_merge<<<N / 4, 256, 0, stream>>>(cs, ct, partials);
    k_reduce<<<1, 256, 0, stream>>>(partials, out);
}